// Round 10
// baseline (651.546 us; speedup 1.0000x reference)
//
#include <hip/hip_runtime.h>
#include <hip/hip_bf16.h>
#include <stdint.h>

// MoE FFN, top-1 routing. x:[4,2048,1024] f32, 8 experts, 1024->4096->1024.
// R10: persistent fused FFN1+FFN2 kernel with atomic work queue and
//      per-m-tile done flags (FFN1 256x256 R9 body; FFN2 256x128 2-phase).

#define D_MODEL 1024
#define D_FF    4096
#define NEXP    8
#define NTOK    8192

typedef __attribute__((ext_vector_type(8))) short bf16x8;
typedef __attribute__((ext_vector_type(8))) unsigned short u16x8;
typedef __attribute__((ext_vector_type(4))) unsigned short u16x4;
typedef __attribute__((ext_vector_type(4))) float f32x4;

// ---- workspace layout (bytes) ----
#define OFF_META 0u
#define OFF_TOPI 4096u
#define OFF_PERM 36864u
#define OFF_POS  69632u
#define OFF_XG   131072u                     // 8448*1024*2
#define OFF_H    17432576u                   // 8448*4096*2
#define OFF_W1T  86638592u                   // 8*4096*1024*2
#define OFF_W2T  153747456u                  // 8*1024*4096*2

__device__ __forceinline__ unsigned short f2bf(float f) {
  unsigned int u = __builtin_bit_cast(unsigned int, f);
  unsigned int r = (u + 0x7FFFu + ((u >> 16) & 1u)) >> 16;
  return (unsigned short)r;
}

typedef const __attribute__((address_space(1))) unsigned int* gas_u32;
typedef __attribute__((address_space(3))) unsigned int* las_u32;

__device__ __forceinline__ void gload16(const void* g, void* l) {
  __builtin_amdgcn_global_load_lds((gas_u32)g, (las_u32)l, 16, 0, 0);
}

// ---------------- gating: one wave per token, fp64 accumulate ----------------
__global__ __launch_bounds__(256) void gate_kernel(const float* __restrict__ x,
    const float* __restrict__ gw, const float* __restrict__ gb,
    const float* __restrict__ eb, int* __restrict__ topi) {
  int wid = threadIdx.x >> 6, lane = threadIdx.x & 63;
  int t = blockIdx.x * 4 + wid;
  const float* xr = x + (size_t)t * D_MODEL;
  double p[NEXP];
#pragma unroll
  for (int e = 0; e < NEXP; ++e) p[e] = 0.0;
#pragma unroll
  for (int j = 0; j < 4; ++j) {
    int c = (lane + j * 64) * 4;
    f32x4 xv = *(const f32x4*)(xr + c);
#pragma unroll
    for (int e = 0; e < NEXP; ++e) {
      f32x4 gv = *(const f32x4*)(gw + e * D_MODEL + c);
#pragma unroll
      for (int q = 0; q < 4; ++q) p[e] += (double)xv[q] * (double)gv[q];
    }
  }
#pragma unroll
  for (int e = 0; e < NEXP; ++e) {
    for (int off = 32; off; off >>= 1) p[e] += __shfl_xor(p[e], off, 64);
  }
  if (lane == 0) {
    double best = -1e300; int bi = 0;
#pragma unroll
    for (int e = 0; e < NEXP; ++e) {
      double v = p[e] + (double)gb[e] + (double)eb[e];
      if (v > best) { best = v; bi = e; }
    }
    topi[t] = bi;
  }
}

// ---- rank kernel: 1 block, 1024 threads. counts/offsets/tilemap/pos/perm ----
__global__ __launch_bounds__(1024) void rank_kernel(const int* __restrict__ topi,
    int* __restrict__ meta, int* __restrict__ pos, int* __restrict__ perm) {
  __shared__ int hist[NEXP][1024];
  __shared__ int offs_s[NEXP + 1];
  int tid = threadIdx.x;
  int te[8], loc[NEXP], run[NEXP];
#pragma unroll
  for (int e = 0; e < NEXP; ++e) loc[e] = 0;
#pragma unroll
  for (int j = 0; j < 8; ++j) {
    te[j] = topi[tid * 8 + j];
#pragma unroll
    for (int e = 0; e < NEXP; ++e) loc[e] += (te[j] == e) ? 1 : 0;
  }
#pragma unroll
  for (int e = 0; e < NEXP; ++e) { run[e] = loc[e]; hist[e][tid] = run[e]; }
  __syncthreads();
  for (int s = 1; s < 1024; s <<= 1) {
    int v[NEXP];
#pragma unroll
    for (int e = 0; e < NEXP; ++e) v[e] = (tid >= s) ? hist[e][tid - s] : 0;
    __syncthreads();
#pragma unroll
    for (int e = 0; e < NEXP; ++e) { run[e] += v[e]; hist[e][tid] = run[e]; }
    __syncthreads();
  }
  if (tid == 1023) {
    int o = 0, nt = 0;
    for (int e = 0; e < NEXP; ++e) {
      offs_s[e] = o;
      meta[e] = run[e];
      meta[8 + e] = o;
      o += run[e];
    }
    offs_s[NEXP] = o; meta[16] = o;
    for (int e = 0; e < NEXP; ++e) {
      int ntile = (run[e] + 255) >> 8;        // 256-row m-tiles
      for (int j = 0; j < ntile; ++j) { meta[32 + nt] = e; meta[112 + nt] = j; ++nt; }
    }
    meta[25] = nt;
    meta[160] = 0;                            // queue head
    for (int i = 0; i < 40; ++i) meta[192 + i] = 0;  // done flags
  }
  __syncthreads();
  int base[NEXP];
#pragma unroll
  for (int e = 0; e < NEXP; ++e) base[e] = offs_s[e] + run[e] - loc[e];
#pragma unroll
  for (int j = 0; j < 8; ++j) {
    int tok = tid * 8 + j, pj = 0;
#pragma unroll
    for (int e = 0; e < NEXP; ++e) {
      if (te[j] == e) pj = base[e];
      base[e] += (te[j] == e) ? 1 : 0;
    }
    pos[tok] = pj;
    perm[pj] = tok;
  }
}

// -------- scatter tokens into per-expert contiguous rows, f32 -> bf16 --------
__global__ __launch_bounds__(256) void scatter_kernel(const float* __restrict__ x,
    const int* __restrict__ pos, unsigned short* __restrict__ xg) {
  int t = blockIdx.x;
  int p = pos[t];
  const float* xr = x + (size_t)t * D_MODEL;
  unsigned short* orow = xg + (size_t)p * D_MODEL;
  int c = threadIdx.x * 4;
  f32x4 v = *(const f32x4*)(xr + c);
  u16x4 u;
#pragma unroll
  for (int j = 0; j < 4; ++j) u[j] = f2bf(v[j]);
  *(u16x4*)(orow + c) = u;
}

// ---- merged weight convert+transpose: [E][R][C] f32 -> [E][C][R] bf16 ----
__global__ __launch_bounds__(256) void transconv_all(
    const float* __restrict__ w1, unsigned short* __restrict__ w1t,
    const float* __restrict__ w2, unsigned short* __restrict__ w2t) {
  __shared__ float tile[64][65];
  int id = blockIdx.x;
  const float* src; unsigned short* dst; int R, C, c0, r0;
  if (id < 8192) {
    int e = id >> 10, rem = id & 1023;
    R = 1024; C = 4096;
    c0 = (rem & 63) * 64; r0 = (rem >> 6) * 64;
    src = w1 + (size_t)e * R * C; dst = w1t + (size_t)e * R * C;
  } else {
    int e = (id - 8192) >> 10, rem = (id - 8192) & 1023;
    R = 4096; C = 1024;
    c0 = (rem & 15) * 64; r0 = (rem >> 4) * 64;
    src = w2 + (size_t)e * R * C; dst = w2t + (size_t)e * R * C;
  }
  int tid = threadIdx.x;
  int rr = tid >> 4, cc4 = (tid & 15) * 4;
#pragma unroll
  for (int i = 0; i < 4; ++i) {
    f32x4 v = *(const f32x4*)(src + (size_t)(r0 + rr + i * 16) * C + c0 + cc4);
#pragma unroll
    for (int j = 0; j < 4; ++j) tile[rr + i * 16][cc4 + j] = v[j];
  }
  __syncthreads();
  int cc = tid >> 3, rr8 = (tid & 7) * 8;
#pragma unroll
  for (int i = 0; i < 2; ++i) {
    int c = cc + i * 32;
    u16x8 u;
#pragma unroll
    for (int j = 0; j < 8; ++j) u[j] = f2bf(tile[rr8 + j][c]);
    *(u16x8*)(dst + (size_t)(c0 + c) * R + r0 + rr8) = u;
  }
}

// ------------- fused persistent FFN1+FFN2 (atomic work queue) ---------------
// Jobs [0,j1): FFN1 256x256 tiles (R9 4-phase body). Jobs [j1,j1+j2):
// FFN2 256x128 tiles (2-phase, A retained in regs). Dependency: FFN1 job
// nt-stores H -> threadfence -> done[t]++. FFN2 job spins done[t]==16 then
// threadfence (acquire). Deadlock-free: spins begin only after FFN1 queue
// fully popped; popped jobs execute on running blocks.
#define SBAR() { __builtin_amdgcn_sched_barrier(0); __builtin_amdgcn_s_barrier(); __builtin_amdgcn_sched_barrier(0); }
#define WAIT_VM(N) { asm volatile("s_waitcnt vmcnt(" #N ")" ::: "memory"); __builtin_amdgcn_sched_barrier(0); }
#define WAIT_LGKM() { asm volatile("s_waitcnt lgkmcnt(0)" ::: "memory"); __builtin_amdgcn_sched_barrier(0); }

__global__ __launch_bounds__(512, 1) void moe_fused(
    const unsigned short* __restrict__ XG, const unsigned short* __restrict__ W1T,
    const unsigned short* __restrict__ W2T, const float* __restrict__ B1,
    const float* __restrict__ B2, int* __restrict__ meta,
    const int* __restrict__ perm, unsigned short* __restrict__ H,
    float* __restrict__ Out) {
  __shared__ char lds[131072];
  __shared__ int sj;
  const int ntiles = meta[25];
  const int j1 = ntiles * 16;                // FFN1: 16 n-panels of 256
  const int j2 = ntiles * 8;                 // FFN2: 8 n-panels of 128
  int* qhead = meta + 160;
  int* done  = meta + 192;

  int tid = threadIdx.x;
  int lane = tid & 63, wv = tid >> 6;
  int waveM = wv >> 2, waveN = wv & 3;       // 2M x 4N
  int lr = lane & 15, lg = lane >> 4;

  const int o0 = tid * 16, o1 = o0 + 8192;
  const int lw0 = o0 >> 7, lw1 = o1 >> 7;
  const int co0 = (o0 & 127) ^ ((lw0 & 7) << 4);
  const int co1 = (o1 & 127) ^ ((lw1 & 7) << 4);
  const int mA0 = (lw0 >> 6) * 128 + (lw0 & 63), mA1 = (lw1 >> 6) * 128 + (lw1 & 63);
  const int nB0 = (lw0 >> 5) * 64 + (lw0 & 31), nB1 = (lw1 >> 5) * 64 + (lw1 & 31);

  for (;;) {
    __syncthreads();
    if (tid == 0) sj = atomicAdd(qhead, 1);
    __syncthreads();
    int j = sj;
    if (j >= j1 + j2) return;

    if (j < j1) {
      // ---------------- FFN1: 256x256, K=1024, 4-phase (R9) ----------------
      int t = j >> 4, nb = j & 15;
      int e = meta[32 + t];
      int lm = meta[112 + t];
      int off = meta[8 + e];
      int rowsValid = meta[9 + e] - off - lm * 256;
      int m0 = off + lm * 256;
      const char* aBase = (const char*)(XG + (size_t)m0 * D_MODEL);
      const char* bBase = (const char*)(W1T + ((size_t)e * D_FF + nb * 256) * D_MODEL);
      const int SK = D_MODEL * 2;
      const int NT = D_MODEL / 64;

#define ST_A1(D, R, KT) { \
    char* _d = lds + (D) * 65536 + (R) * 16384; \
    gload16(aBase + (size_t)(mA0 + (R) * 64) * SK + (KT) * 128 + co0, _d + o0); \
    gload16(aBase + (size_t)(mA1 + (R) * 64) * SK + (KT) * 128 + co1, _d + o1); }
#define ST_B1(D, R, KT) { \
    char* _d = lds + (D) * 65536 + 32768 + (R) * 16384; \
    gload16(bBase + (size_t)(nB0 + (R) * 32) * SK + (KT) * 128 + co0, _d + o0); \
    gload16(bBase + (size_t)(nB1 + (R) * 32) * SK + (KT) * 128 + co1, _d + o1); }

      bf16x8 a[4][2], b0[2][2], b1[2][2];
#define LD_A1(D, MH) { \
    const char* _b = lds + (D) * 65536 + (MH) * 16384; \
    _Pragma("unroll") for (int mfi = 0; mfi < 4; ++mfi) \
    _Pragma("unroll") for (int ks = 0; ks < 2; ++ks) { \
      int _o = (waveM * 64 + mfi * 16 + lr) * 128 + ks * 64 + lg * 16; \
      _o ^= ((_o >> 7) & 7) << 4; \
      a[mfi][ks] = *(const bf16x8*)(_b + _o); } }
#define LD_B1(D, NH, BV) { \
    const char* _b = lds + (D) * 65536 + 32768 + (NH) * 16384; \
    _Pragma("unroll") for (int nfi = 0; nfi < 2; ++nfi) \
    _Pragma("unroll") for (int ks = 0; ks < 2; ++ks) { \
      int _o = (waveN * 32 + nfi * 16 + lr) * 128 + ks * 64 + lg * 16; \
      _o ^= ((_o >> 7) & 7) << 4; \
      BV[nfi][ks] = *(const bf16x8*)(_b + _o); } }

      f32x4 acc[8][4];
#pragma unroll
      for (int i = 0; i < 8; ++i)
#pragma unroll
        for (int jq = 0; jq < 4; ++jq) acc[i][jq] = (f32x4){0.f, 0.f, 0.f, 0.f};

#define MM1(MH, NH, BV) { \
    WAIT_LGKM(); \
    __builtin_amdgcn_s_setprio(1); \
    _Pragma("unroll") for (int mfi = 0; mfi < 4; ++mfi) \
    _Pragma("unroll") for (int nfi = 0; nfi < 2; ++nfi) \
    _Pragma("unroll") for (int ks = 0; ks < 2; ++ks) \
      acc[(MH) * 4 + mfi][(NH) * 2 + nfi] = __builtin_amdgcn_mfma_f32_16x16x32_bf16( \
          a[mfi][ks], BV[nfi][ks], acc[(MH) * 4 + mfi][(NH) * 2 + nfi], 0, 0, 0); \
    __builtin_amdgcn_s_setprio(0); }

      ST_A1(0, 0, 0); ST_B1(0, 1, 0); ST_A1(0, 1, 0); ST_B1(0, 0, 0);
      ST_A1(1, 0, 1); ST_B1(1, 1, 1); ST_A1(1, 1, 1);
      WAIT_VM(6); SBAR();

      for (int T = 0; T < NT; ++T) {
        int d = T & 1, dn = d ^ 1;
        int tp1 = T + 1 < NT ? T + 1 : T;
        int tp2 = T + 2 < NT ? T + 2 : T;
        LD_A1(d, 0); LD_B1(d, 0, b0);
        ST_B1(dn, 0, tp1);
        SBAR();
        MM1(0, 0, b0);
        SBAR();
        LD_B1(d, 1, b1);
        ST_A1(d, 0, tp2);
        SBAR();
        MM1(0, 1, b1);
        SBAR();
        LD_A1(d, 1);
        ST_B1(d, 1, tp2);
        SBAR();
        MM1(1, 1, b1);
        SBAR();
        ST_A1(d, 1, tp2);
        SBAR();
        MM1(1, 0, b0);
        WAIT_VM(6);
        SBAR();
      }
      asm volatile("s_waitcnt vmcnt(0)" ::: "memory");

      int cb = nb * 256 + waveN * 64;
#pragma unroll
      for (int mf = 0; mf < 8; ++mf) {
#pragma unroll
        for (int rg = 0; rg < 4; ++rg) {
          int rowt = waveM * 128 + mf * 16 + lg * 4 + rg;
          if (rowt >= rowsValid) continue;
          size_t ro = (size_t)(m0 + rowt) * D_FF;
#pragma unroll
          for (int nf = 0; nf < 4; ++nf) {
            int col = cb + nf * 16 + lr;
            float v = acc[mf][nf][rg] + B1[e * D_FF + col];
            __builtin_nontemporal_store(f2bf(fmaxf(v, 0.f)), &H[ro + col]);
          }
        }
      }
      __threadfence();
      __syncthreads();
      if (tid == 0) atomicAdd(done + t, 1);
#undef ST_A1
#undef ST_B1
#undef LD_A1
#undef LD_B1
#undef MM1
    } else {
      // ------------- FFN2: 256x128, K=4096, 2-phase, A in regs -------------
      int jj = j - j1;
      int t = jj >> 3, nb = jj & 7;
      if (tid == 0) {
        while (__hip_atomic_load(done + t, __ATOMIC_RELAXED, __HIP_MEMORY_SCOPE_AGENT) < 16)
          __builtin_amdgcn_s_sleep(2);
      }
      __syncthreads();
      __threadfence();   // acquire: invalidate caches before reading H

      int e = meta[32 + t];
      int lm = meta[112 + t];
      int off = meta[8 + e];
      int rowsValid = meta[9 + e] - off - lm * 256;
      int m0 = off + lm * 256;
      const char* aBase = (const char*)(H + (size_t)m0 * D_FF);
      const char* bBase = (const char*)(W2T + ((size_t)e * D_MODEL + nb * 128) * D_FF);
      const int SK = D_FF * 2;
      const int NT = D_FF / 64;

      // LDS: A bufs 2x32KB at 0; B bufs 2x16KB at 65536.
#define ST_A2(D, KT) { \
    char* _d = lds + (D) * 32768; \
    _Pragma("unroll") for (int _q = 0; _q < 4; ++_q) { \
      int _o = tid * 16 + _q * 8192; \
      int _lw = _o >> 7; \
      int _co = (_o & 127) ^ ((_lw & 7) << 4); \
      gload16(aBase + (size_t)_lw * SK + (KT) * 128 + _co, _d + _o); } }
#define ST_B2(D, KT) { \
    char* _d = lds + 65536 + (D) * 16384; \
    _Pragma("unroll") for (int _q = 0; _q < 2; ++_q) { \
      int _o = tid * 16 + _q * 8192; \
      int _lw = _o >> 7; \
      int _co = (_o & 127) ^ ((_lw & 7) << 4); \
      gload16(bBase + (size_t)_lw * SK + (KT) * 128 + _co, _d + _o); } }

      bf16x8 a2[8][2], b2[2][2];
#define LD_A2(D) { \
    const char* _b = lds + (D) * 32768; \
    _Pragma("unroll") for (int mfi = 0; mfi < 8; ++mfi) \
    _Pragma("unroll") for (int ks = 0; ks < 2; ++ks) { \
      int _o = (waveM * 128 + mfi * 16 + lr) * 128 + ks * 64 + lg * 16; \
      _o ^= ((_o >> 7) & 7) << 4; \
      a2[mfi][ks] = *(const bf16x8*)(_b + _o); } }
#define LD_B2(D) { \
    const char* _b = lds + 65536 + (D) * 16384; \
    _Pragma("unroll") for (int nfi = 0; nfi < 2; ++nfi) \
    _Pragma("unroll") for (int ks = 0; ks < 2; ++ks) { \
      int _o = (waveN * 32 + nfi * 16 + lr) * 128 + ks * 64 + lg * 16; \
      _o ^= ((_o >> 7) & 7) << 4; \
      b2[nfi][ks] = *(const bf16x8*)(_b + _o); } }

      f32x4 acc2[8][2];
#pragma unroll
      for (int i = 0; i < 8; ++i)
#pragma unroll
        for (int jq = 0; jq < 2; ++jq) acc2[i][jq] = (f32x4){0.f, 0.f, 0.f, 0.f};

#define MM2(MH) { \
    __builtin_amdgcn_s_setprio(1); \
    _Pragma("unroll") for (int mfi = 0; mfi < 4; ++mfi) \
    _Pragma("unroll") for (int nfi = 0; nfi < 2; ++nfi) \
    _Pragma("unroll") for (int ks = 0; ks < 2; ++ks) \
      acc2[(MH) * 4 + mfi][nfi] = __builtin_amdgcn_mfma_f32_16x16x32_bf16( \
          a2[(MH) * 4 + mfi][ks], b2[nfi][ks], acc2[(MH) * 4 + mfi][nfi], 0, 0, 0); \
    __builtin_amdgcn_s_setprio(0); }

      // prologue: A(0)x4, B(0)x2, A(1)x4 -> wait(4): tile0 landed, A(1) flying
      ST_A2(0, 0); ST_B2(0, 0); ST_A2(1, 1);
      WAIT_VM(4); SBAR();

      for (int T = 0; T < NT; ++T) {
        int d = T & 1, dn = d ^ 1;
        int tp1 = T + 1 < NT ? T + 1 : T;
        int tp2 = T + 2 < NT ? T + 2 : T;
        // p1: read ALL of A(d) + B(d); stage B(T+1) -> dn
        LD_A2(d); LD_B2(d);
        ST_B2(dn, tp1);
        SBAR();
        WAIT_LGKM();
        __builtin_amdgcn_s_setprio(1);
        MM2(0);
        __builtin_amdgcn_s_setprio(0);
        SBAR();
        // p2: no LDS reads (a2 retained); stage A(T+2) -> d (reads done p1)
        ST_A2(d, tp2);
        SBAR();
        MM2(1);
        WAIT_VM(4);
        SBAR();
      }
      asm volatile("s_waitcnt vmcnt(0)" ::: "memory");

      int cb = nb * 128 + waveN * 32;
#pragma unroll
      for (int mf = 0; mf < 8; ++mf) {
#pragma unroll
        for (int rg = 0; rg < 4; ++rg) {
          int rowt = waveM * 128 + mf * 16 + lg * 4 + rg;
          if (rowt >= rowsValid) continue;
          int tok = perm[m0 + rowt];
          size_t ro = (size_t)tok * D_MODEL;
#pragma unroll
          for (int nf = 0; nf < 2; ++nf) {
            int col = cb + nf * 16 + lr;
            Out[ro + col] = acc2[mf][nf][rg] + B2[e * D_MODEL + col];
          }
        }
      }
#undef ST_A2
#undef ST_B2
#undef LD_A2
#undef LD_B2
#undef MM2
    }
  }
}

extern "C" void kernel_launch(void* const* d_in, const int* in_sizes, int n_in,
                              void* d_out, int out_size, void* d_ws, size_t ws_size,
                              hipStream_t stream) {
  const float* x  = (const float*)d_in[0];
  const float* gw = (const float*)d_in[1];
  const float* gb = (const float*)d_in[2];
  const float* eb = (const float*)d_in[3];
  const float* w1 = (const float*)d_in[4];
  const float* b1 = (const float*)d_in[5];
  const float* w2 = (const float*)d_in[6];
  const float* b2 = (const float*)d_in[7];
  float* out = (float*)d_out;

  char* ws = (char*)d_ws;
  int* meta = (int*)(ws + OFF_META);
  int* topi = (int*)(ws + OFF_TOPI);
  int* perm = (int*)(ws + OFF_PERM);
  int* pos  = (int*)(ws + OFF_POS);
  unsigned short* xg  = (unsigned short*)(ws + OFF_XG);
  unsigned short* h   = (unsigned short*)(ws + OFF_H);
  unsigned short* w1t = (unsigned short*)(ws + OFF_W1T);
  unsigned short* w2t = (unsigned short*)(ws + OFF_W2T);

  hipLaunchKernelGGL(gate_kernel, dim3(NTOK / 4), dim3(256), 0, stream, x, gw, gb, eb, topi);
  hipLaunchKernelGGL(rank_kernel, dim3(1), dim3(1024), 0, stream, topi, meta, pos, perm);
  hipLaunchKernelGGL(scatter_kernel, dim3(NTOK), dim3(256), 0, stream, x, pos, xg);
  hipLaunchKernelGGL(transconv_all, dim3(16384), dim3(256), 0, stream, w1, w1t, w2, w2t);
  hipLaunchKernelGGL(moe_fused, dim3(256), dim3(512), 0, stream,
                     xg, w1t, w2t, b1, b2, meta, perm, h, out);
}

// Round 11
// 343.578 us; speedup vs baseline: 1.8964x; 1.8964x over previous
//
#include <hip/hip_runtime.h>
#include <hip/hip_bf16.h>
#include <stdint.h>

// MoE FFN, top-1 routing. x:[4,2048,1024] f32, 8 experts, 1024->4096->1024.
// R11: R9 routing + barrier-light 256x256 GEMM: strict T+1 double-buffer
//      (stage only to the non-read buffer) -> ZERO intra-tile barriers,
//      one vmcnt(0)+barrier per K-tile, compiler free to pipeline ds_read/MFMA.

#define D_MODEL 1024
#define D_FF    4096
#define NEXP    8
#define NTOK    8192
#define MAXT256 40

typedef __attribute__((ext_vector_type(8))) short bf16x8;
typedef __attribute__((ext_vector_type(8))) unsigned short u16x8;
typedef __attribute__((ext_vector_type(4))) unsigned short u16x4;
typedef __attribute__((ext_vector_type(4))) float f32x4;

// ---- workspace layout (bytes) ----
#define OFF_META 0u
#define OFF_TOPI 4096u
#define OFF_PERM 36864u
#define OFF_POS  69632u
#define OFF_XG   131072u                     // 8448*1024*2
#define OFF_H    17432576u                   // 8448*4096*2
#define OFF_W1T  86638592u                   // 8*4096*1024*2
#define OFF_W2T  153747456u                  // 8*1024*4096*2

__device__ __forceinline__ unsigned short f2bf(float f) {
  unsigned int u = __builtin_bit_cast(unsigned int, f);
  unsigned int r = (u + 0x7FFFu + ((u >> 16) & 1u)) >> 16;
  return (unsigned short)r;
}

typedef const __attribute__((address_space(1))) unsigned int* gas_u32;
typedef __attribute__((address_space(3))) unsigned int* las_u32;

__device__ __forceinline__ void gload16(const void* g, void* l) {
  __builtin_amdgcn_global_load_lds((gas_u32)g, (las_u32)l, 16, 0, 0);
}

__device__ __forceinline__ int xcd_swz(int orig, int nwg) {
  int q = nwg >> 3, r = nwg & 7;
  int xcd = orig & 7, lid = orig >> 3;
  return (xcd < r ? xcd * (q + 1) : r * (q + 1) + (xcd - r) * q) + lid;
}

// ---------------- gating: one wave per token, fp64 accumulate ----------------
__global__ __launch_bounds__(256) void gate_kernel(const float* __restrict__ x,
    const float* __restrict__ gw, const float* __restrict__ gb,
    const float* __restrict__ eb, int* __restrict__ topi) {
  int wid = threadIdx.x >> 6, lane = threadIdx.x & 63;
  int t = blockIdx.x * 4 + wid;
  const float* xr = x + (size_t)t * D_MODEL;
  double p[NEXP];
#pragma unroll
  for (int e = 0; e < NEXP; ++e) p[e] = 0.0;
#pragma unroll
  for (int j = 0; j < 4; ++j) {
    int c = (lane + j * 64) * 4;
    f32x4 xv = *(const f32x4*)(xr + c);
#pragma unroll
    for (int e = 0; e < NEXP; ++e) {
      f32x4 gv = *(const f32x4*)(gw + e * D_MODEL + c);
#pragma unroll
      for (int q = 0; q < 4; ++q) p[e] += (double)xv[q] * (double)gv[q];
    }
  }
#pragma unroll
  for (int e = 0; e < NEXP; ++e) {
    for (int off = 32; off; off >>= 1) p[e] += __shfl_xor(p[e], off, 64);
  }
  if (lane == 0) {
    double best = -1e300; int bi = 0;
#pragma unroll
    for (int e = 0; e < NEXP; ++e) {
      double v = p[e] + (double)gb[e] + (double)eb[e];
      if (v > best) { best = v; bi = e; }
    }
    topi[t] = bi;
  }
}

// ---- rank kernel: 1 block, 1024 threads. counts/offsets/tilemap/pos/perm ----
__global__ __launch_bounds__(1024) void rank_kernel(const int* __restrict__ topi,
    int* __restrict__ meta, int* __restrict__ pos, int* __restrict__ perm) {
  __shared__ int hist[NEXP][1024];
  __shared__ int offs_s[NEXP + 1];
  int tid = threadIdx.x;
  int te[8], loc[NEXP], run[NEXP];
#pragma unroll
  for (int e = 0; e < NEXP; ++e) loc[e] = 0;
#pragma unroll
  for (int j = 0; j < 8; ++j) {
    te[j] = topi[tid * 8 + j];
#pragma unroll
    for (int e = 0; e < NEXP; ++e) loc[e] += (te[j] == e) ? 1 : 0;
  }
#pragma unroll
  for (int e = 0; e < NEXP; ++e) { run[e] = loc[e]; hist[e][tid] = run[e]; }
  __syncthreads();
  for (int s = 1; s < 1024; s <<= 1) {
    int v[NEXP];
#pragma unroll
    for (int e = 0; e < NEXP; ++e) v[e] = (tid >= s) ? hist[e][tid - s] : 0;
    __syncthreads();
#pragma unroll
    for (int e = 0; e < NEXP; ++e) { run[e] += v[e]; hist[e][tid] = run[e]; }
    __syncthreads();
  }
  if (tid == 1023) {
    int o = 0, nt = 0;
    for (int e = 0; e < NEXP; ++e) {
      offs_s[e] = o;
      meta[e] = run[e];
      meta[8 + e] = o;
      o += run[e];
    }
    offs_s[NEXP] = o; meta[16] = o;
    for (int e = 0; e < NEXP; ++e) {
      int ntile = (run[e] + 255) >> 8;        // 256-row m-tiles
      for (int j = 0; j < ntile; ++j) { meta[32 + nt] = e; meta[112 + nt] = j; ++nt; }
    }
    meta[25] = nt;
  }
  __syncthreads();
  int base[NEXP];
#pragma unroll
  for (int e = 0; e < NEXP; ++e) base[e] = offs_s[e] + run[e] - loc[e];
#pragma unroll
  for (int j = 0; j < 8; ++j) {
    int tok = tid * 8 + j, pj = 0;
#pragma unroll
    for (int e = 0; e < NEXP; ++e) {
      if (te[j] == e) pj = base[e];
      base[e] += (te[j] == e) ? 1 : 0;
    }
    pos[tok] = pj;
    perm[pj] = tok;
  }
}

// -------- scatter tokens into per-expert contiguous rows, f32 -> bf16 --------
__global__ __launch_bounds__(256) void scatter_kernel(const float* __restrict__ x,
    const int* __restrict__ pos, unsigned short* __restrict__ xg) {
  int t = blockIdx.x;
  int p = pos[t];
  const float* xr = x + (size_t)t * D_MODEL;
  unsigned short* orow = xg + (size_t)p * D_MODEL;
  int c = threadIdx.x * 4;
  f32x4 v = *(const f32x4*)(xr + c);
  u16x4 u;
#pragma unroll
  for (int j = 0; j < 4; ++j) u[j] = f2bf(v[j]);
  *(u16x4*)(orow + c) = u;
}

// ---- merged weight convert+transpose: [E][R][C] f32 -> [E][C][R] bf16 ----
__global__ __launch_bounds__(256) void transconv_all(
    const float* __restrict__ w1, unsigned short* __restrict__ w1t,
    const float* __restrict__ w2, unsigned short* __restrict__ w2t) {
  __shared__ float tile[64][65];
  int id = blockIdx.x;
  const float* src; unsigned short* dst; int R, C, c0, r0;
  if (id < 8192) {
    int e = id >> 10, rem = id & 1023;
    R = 1024; C = 4096;
    c0 = (rem & 63) * 64; r0 = (rem >> 6) * 64;
    src = w1 + (size_t)e * R * C; dst = w1t + (size_t)e * R * C;
  } else {
    int e = (id - 8192) >> 10, rem = (id - 8192) & 1023;
    R = 4096; C = 1024;
    c0 = (rem & 15) * 64; r0 = (rem >> 4) * 64;
    src = w2 + (size_t)e * R * C; dst = w2t + (size_t)e * R * C;
  }
  int tid = threadIdx.x;
  int rr = tid >> 4, cc4 = (tid & 15) * 4;
#pragma unroll
  for (int i = 0; i < 4; ++i) {
    f32x4 v = *(const f32x4*)(src + (size_t)(r0 + rr + i * 16) * C + c0 + cc4);
#pragma unroll
    for (int j = 0; j < 4; ++j) tile[rr + i * 16][cc4 + j] = v[j];
  }
  __syncthreads();
  int cc = tid >> 3, rr8 = (tid & 7) * 8;
#pragma unroll
  for (int i = 0; i < 2; ++i) {
    int c = cc + i * 32;
    u16x8 u;
#pragma unroll
    for (int j = 0; j < 8; ++j) u[j] = f2bf(tile[rr8 + j][c]);
    *(u16x8*)(dst + (size_t)(c0 + c) * R + r0 + rr8) = u;
  }
}

// ---------- barrier-light 256x256 grouped GEMM (bf16 MFMA) ------------------
// A [rows][KDIM] bf16, Bt [E][NDIM][KDIM] bf16. 8 waves 2Mx4N, BK=64.
// LDS 128KB: strict double-buffer. During tile T: ALL stages (8 gloads,
// issued at tile top) target buf dn = T+1's buffer; ALL reads from buf d.
// No intra-tile hazards -> no intra-tile barriers; compiler pipelines
// ds_read with MFMA freely. One WAIT_VM(0)+barrier per K-tile (loads were
// issued a full tile earlier, drain mostly amortized).
// Swizzle both sides: byte ^= ((row&7)<<4).
#define SBAR() { __builtin_amdgcn_sched_barrier(0); __builtin_amdgcn_s_barrier(); __builtin_amdgcn_sched_barrier(0); }
#define WAIT_VM0() { asm volatile("s_waitcnt vmcnt(0)" ::: "memory"); __builtin_amdgcn_sched_barrier(0); }

template<int KDIM, int NDIM, bool IS_FFN1>
__global__ __launch_bounds__(512, 1) void gemm8(
    const unsigned short* __restrict__ A, const unsigned short* __restrict__ Bt,
    const float* __restrict__ bias, const int* __restrict__ meta,
    const int* __restrict__ perm, unsigned short* __restrict__ H,
    float* __restrict__ Out) {
  constexpr int NT = KDIM / 64;
  constexpr int SK = KDIM * 2;
  const int NP = NDIM / 256;
  int ntiles = meta[25];
  int nwg = ntiles * NP;
  int orig = blockIdx.x;
  if (orig >= nwg) return;
  int wid = xcd_swz(orig, nwg);
  int t = wid % ntiles, nb = wid / ntiles;   // n-outer, m-inner

  int e = meta[32 + t];
  int lm = meta[112 + t];
  int off = meta[8 + e];
  int rowsValid = meta[9 + e] - off - lm * 256;
  int m0 = off + lm * 256;

  __shared__ char lds[131072];

  int tid = threadIdx.x;
  int lane = tid & 63, wv = tid >> 6;
  int waveM = wv >> 2, waveN = wv & 3;       // 2M x 4N
  int lr = lane & 15, lg = lane >> 4;

  const char* aBase = (const char*)(A + (size_t)m0 * KDIM);
  const char* bBase = (const char*)(Bt + ((size_t)e * NDIM + nb * 256) * KDIM);

  const int o0 = tid * 16, o1 = o0 + 8192;
  const int lw0 = o0 >> 7, lw1 = o1 >> 7;
  const int co0 = (o0 & 127) ^ ((lw0 & 7) << 4);
  const int co1 = (o1 & 127) ^ ((lw1 & 7) << 4);
  const int mA0 = (lw0 >> 6) * 128 + (lw0 & 63), mA1 = (lw1 >> 6) * 128 + (lw1 & 63);
  const int nB0 = (lw0 >> 5) * 64 + (lw0 & 31), nB1 = (lw1 >> 5) * 64 + (lw1 & 31);

#define ST_A(D, R, KT) { \
    char* _d = lds + (D) * 65536 + (R) * 16384; \
    gload16(aBase + (size_t)(mA0 + (R) * 64) * SK + (KT) * 128 + co0, _d + o0); \
    gload16(aBase + (size_t)(mA1 + (R) * 64) * SK + (KT) * 128 + co1, _d + o1); }
#define ST_B(D, R, KT) { \
    char* _d = lds + (D) * 65536 + 32768 + (R) * 16384; \
    gload16(bBase + (size_t)(nB0 + (R) * 32) * SK + (KT) * 128 + co0, _d + o0); \
    gload16(bBase + (size_t)(nB1 + (R) * 32) * SK + (KT) * 128 + co1, _d + o1); }

  bf16x8 a[4][2], b0[2][2], b1[2][2];
#define LD_A(D, MH) { \
    const char* _b = lds + (D) * 65536 + (MH) * 16384; \
    _Pragma("unroll") for (int mfi = 0; mfi < 4; ++mfi) \
    _Pragma("unroll") for (int ks = 0; ks < 2; ++ks) { \
      int _o = (waveM * 64 + mfi * 16 + lr) * 128 + ks * 64 + lg * 16; \
      _o ^= ((_o >> 7) & 7) << 4; \
      a[mfi][ks] = *(const bf16x8*)(_b + _o); } }
#define LD_B(D, NH, BV) { \
    const char* _b = lds + (D) * 65536 + 32768 + (NH) * 16384; \
    _Pragma("unroll") for (int nfi = 0; nfi < 2; ++nfi) \
    _Pragma("unroll") for (int ks = 0; ks < 2; ++ks) { \
      int _o = (waveN * 32 + nfi * 16 + lr) * 128 + ks * 64 + lg * 16; \
      _o ^= ((_o >> 7) & 7) << 4; \
      BV[nfi][ks] = *(const bf16x8*)(_b + _o); } }

  f32x4 acc[8][4];
#pragma unroll
  for (int i = 0; i < 8; ++i)
#pragma unroll
    for (int j = 0; j < 4; ++j) acc[i][j] = (f32x4){0.f, 0.f, 0.f, 0.f};

#define MM(MH, NH, BV) { \
    __builtin_amdgcn_s_setprio(1); \
    _Pragma("unroll") for (int mfi = 0; mfi < 4; ++mfi) \
    _Pragma("unroll") for (int nfi = 0; nfi < 2; ++nfi) \
    _Pragma("unroll") for (int ks = 0; ks < 2; ++ks) \
      acc[(MH) * 4 + mfi][(NH) * 2 + nfi] = __builtin_amdgcn_mfma_f32_16x16x32_bf16( \
          a[mfi][ks], BV[nfi][ks], acc[(MH) * 4 + mfi][(NH) * 2 + nfi], 0, 0, 0); \
    __builtin_amdgcn_s_setprio(0); }

  // prologue: stage tile0 -> buf0, drain, sync.
  ST_A(0, 0, 0); ST_B(0, 0, 0); ST_A(0, 1, 0); ST_B(0, 1, 0);
  WAIT_VM0(); SBAR();

  for (int T = 0; T < NT; ++T) {
    int d = T & 1, dn = d ^ 1;
    int tp1 = T + 1 < NT ? T + 1 : T;
    // stage ALL of tile T+1 into dn, issued at tile top (hidden under compute)
    ST_A(dn, 0, tp1); ST_B(dn, 0, tp1); ST_A(dn, 1, tp1); ST_B(dn, 1, tp1);
    // compute tile T from buf d; no intra-tile barriers
    LD_A(d, 0); LD_B(d, 0, b0);
    MM(0, 0, b0);
    LD_B(d, 1, b1);
    MM(0, 1, b1);
    LD_A(d, 1);
    MM(1, 1, b1);
    MM(1, 0, b0);
    // boundary: T+1 loads landed; all waves done reading buf d
    WAIT_VM0();
    SBAR();
  }

  // epilogue: C/D map col=lane&15, row=(lane>>4)*4+reg
  int cb = nb * 256 + waveN * 64;
#pragma unroll
  for (int mf = 0; mf < 8; ++mf) {
#pragma unroll
    for (int rg = 0; rg < 4; ++rg) {
      int rowt = waveM * 128 + mf * 16 + lg * 4 + rg;
      if (rowt >= rowsValid) continue;
      if (IS_FFN1) {
        size_t ro = (size_t)(m0 + rowt) * NDIM;
#pragma unroll
        for (int nf = 0; nf < 4; ++nf) {
          int col = cb + nf * 16 + lr;
          float v = acc[mf][nf][rg] + bias[e * NDIM + col];
          H[ro + col] = f2bf(fmaxf(v, 0.f));
        }
      } else {
        int tok = perm[m0 + rowt];
        size_t ro = (size_t)tok * NDIM;
#pragma unroll
        for (int nf = 0; nf < 4; ++nf) {
          int col = cb + nf * 16 + lr;
          Out[ro + col] = acc[mf][nf][rg] + bias[e * NDIM + col];
        }
      }
    }
  }
#undef ST_A
#undef ST_B
#undef LD_A
#undef LD_B
#undef MM
}

extern "C" void kernel_launch(void* const* d_in, const int* in_sizes, int n_in,
                              void* d_out, int out_size, void* d_ws, size_t ws_size,
                              hipStream_t stream) {
  const float* x  = (const float*)d_in[0];
  const float* gw = (const float*)d_in[1];
  const float* gb = (const float*)d_in[2];
  const float* eb = (const float*)d_in[3];
  const float* w1 = (const float*)d_in[4];
  const float* b1 = (const float*)d_in[5];
  const float* w2 = (const float*)d_in[6];
  const float* b2 = (const float*)d_in[7];
  float* out = (float*)d_out;

  char* ws = (char*)d_ws;
  int* meta = (int*)(ws + OFF_META);
  int* topi = (int*)(ws + OFF_TOPI);
  int* perm = (int*)(ws + OFF_PERM);
  int* pos  = (int*)(ws + OFF_POS);
  unsigned short* xg  = (unsigned short*)(ws + OFF_XG);
  unsigned short* h   = (unsigned short*)(ws + OFF_H);
  unsigned short* w1t = (unsigned short*)(ws + OFF_W1T);
  unsigned short* w2t = (unsigned short*)(ws + OFF_W2T);

  hipLaunchKernelGGL(gate_kernel, dim3(NTOK / 4), dim3(256), 0, stream, x, gw, gb, eb, topi);
  hipLaunchKernelGGL(rank_kernel, dim3(1), dim3(1024), 0, stream, topi, meta, pos, perm);
  hipLaunchKernelGGL(scatter_kernel, dim3(NTOK), dim3(256), 0, stream, x, pos, xg);
  hipLaunchKernelGGL(transconv_all, dim3(16384), dim3(256), 0, stream, w1, w1t, w2, w2t);
  hipLaunchKernelGGL((gemm8<D_MODEL, D_FF, true>), dim3(MAXT256 * (D_FF / 256)), dim3(512), 0, stream,
                     xg, w1t, b1, meta, perm, h, nullptr);
  hipLaunchKernelGGL((gemm8<D_FF, D_MODEL, false>), dim3(MAXT256 * (D_MODEL / 256)), dim3(512), 0, stream,
                     h, w2t, b2, meta, perm, nullptr, out);
}